// Round 13
// baseline (334.894 us; speedup 1.0000x reference)
//
#include <hip/hip_runtime.h>

#define KF 128
#define NSUP 256
#define NSPEC 4
#define GRID 256      // 1 block per CU (LDS-capped)
#define BLOCK 768     // 12 waves -> 3 waves/SIMD

typedef __bf16 bf16x8 __attribute__((ext_vector_type(8)));
typedef float  f32x4  __attribute__((ext_vector_type(4)));

// ---------------- build per-species Gram matrix, sigma-permuted fragment-major ----------------
// G[s][c][k] = sum_m w[s][m]*sup[s][m][c]*sup[s][m][k]  (fp32 accum -> bf16)
// t = ((s*8+ct)*4+kk)*64+lane holds G[s][sigma(ct,lane&15)][kk*32+(lane>>4)*8+u], u=0..7
// sigma(ct,i) = (ct>>1)*32 + (i>>2)*8 + (ct&1)*4 + (i&3): MFMA D-layout lands z[c] on
// the lane that already holds x[c] -> pairing needs no cross-lane moves.

__global__ void k_buildG(const float* __restrict__ sup, const float* __restrict__ w,
                         __bf16* __restrict__ gfrag) {
    const int t = blockIdx.x * blockDim.x + threadIdx.x;   // 8192 total
    if (t >= NSPEC * 8 * 4 * 64) return;
    const int lane = t & 63;
    const int kk   = (t >> 6) & 3;
    const int ct   = (t >> 8) & 7;
    const int s    = t >> 11;
    const int i    = lane & 15;
    const int c    = (ct >> 1) * 32 + (i >> 2) * 8 + (ct & 1) * 4 + (i & 3);
    const int k0   = kk * 32 + (lane >> 4) * 8;
    const float* S = sup + (size_t)s * NSUP * KF;
    const float* W = w + s * NSUP;
    float a0 = 0.f, a1 = 0.f, a2 = 0.f, a3 = 0.f, a4 = 0.f, a5 = 0.f, a6 = 0.f, a7 = 0.f;
    for (int m = 0; m < NSUP; ++m) {
        const float wc = W[m] * S[m * KF + c];
        const float4 ka = *(const float4*)(S + m * KF + k0);
        const float4 kb = *(const float4*)(S + m * KF + k0 + 4);
        a0 += wc * ka.x; a1 += wc * ka.y; a2 += wc * ka.z; a3 += wc * ka.w;
        a4 += wc * kb.x; a5 += wc * kb.y; a6 += wc * kb.z; a7 += wc * kb.w;
    }
    bf16x8 o;
    o[0] = (__bf16)a0; o[1] = (__bf16)a1; o[2] = (__bf16)a2; o[3] = (__bf16)a3;
    o[4] = (__bf16)a4; o[5] = (__bf16)a5; o[6] = (__bf16)a6; o[7] = (__bf16)a7;
    *(bf16x8*)(gfrag + (size_t)t * 8) = o;
}

// ---------------- helpers ----------------

__device__ __forceinline__ bf16x8 pack8(float4 a, float4 b) {
    bf16x8 o;
    o[0] = (__bf16)a.x; o[1] = (__bf16)a.y; o[2] = (__bf16)a.z; o[3] = (__bf16)a.w;
    o[4] = (__bf16)b.x; o[5] = (__bf16)b.y; o[6] = (__bf16)b.z; o[7] = (__bf16)b.w;
    return o;
}

__device__ __forceinline__ float sq4(float4 a) {
    return a.x * a.x + a.y * a.y + a.z * a.z + a.w * a.w;
}

// raw prefetch of one 16-atom set (no data-dependent VALU -> waitcnt lands at consume)
#define PREF_SET(BASE, OFF, SPC, SID, V, Q0, Q1, Q2, Q3, Q4, Q5, Q6, Q7)  \
    {                                                                     \
        int _a = (BASE) + (OFF) + r;                                      \
        V = _a < n;                                                       \
        int _ra = V ? _a : 0;                                             \
        SPC = V ? species[_ra] : -1;                                      \
        SID = V ? sids[_ra] : 0;                                          \
        const float* _p = ps + (size_t)_ra * KF + g * 8;                  \
        Q0 = V ? *(const float4*)(_p +   0) : z4;                         \
        Q1 = V ? *(const float4*)(_p +   4) : z4;                         \
        Q2 = V ? *(const float4*)(_p +  32) : z4;                         \
        Q3 = V ? *(const float4*)(_p +  36) : z4;                         \
        Q4 = V ? *(const float4*)(_p +  64) : z4;                         \
        Q5 = V ? *(const float4*)(_p +  68) : z4;                         \
        Q6 = V ? *(const float4*)(_p +  96) : z4;                         \
        Q7 = V ? *(const float4*)(_p + 100) : z4;                         \
    }

// norm (fp32) + bf16 pack
#define CONSUME_SET(NN, X0, X1, X2, X3, Q0, Q1, Q2, Q3, Q4, Q5, Q6, Q7)   \
    {                                                                     \
        NN = sq4(Q0) + sq4(Q1) + sq4(Q2) + sq4(Q3)                        \
           + sq4(Q4) + sq4(Q5) + sq4(Q6) + sq4(Q7);                       \
        NN += __shfl_xor(NN, 16);                                         \
        NN += __shfl_xor(NN, 32);                                         \
        X0 = pack8(Q0, Q1); X1 = pack8(Q2, Q3);                           \
        X2 = pack8(Q4, Q5); X3 = pack8(Q6, Q7);                           \
    }

// One ct-step for BOTH atom-sets: 4 G-fragment LDS reads feed 8 MFMA.
// Pairing scalars come from fragment XA/XB elements (CT&1)*4 .. +3.
#define GSTEP2(CT, XA, XB)                                                      \
    {                                                                           \
        const __bf16* gq = gp + (CT) * 2048;                                    \
        const bf16x8 g0 = *(const bf16x8*)(gq);                                 \
        const bf16x8 g1 = *(const bf16x8*)(gq + 512);                           \
        const bf16x8 g2 = *(const bf16x8*)(gq + 1024);                          \
        const bf16x8 g3 = *(const bf16x8*)(gq + 1536);                          \
        f32x4 aA = (f32x4){0.f, 0.f, 0.f, 0.f};                                 \
        f32x4 aB = (f32x4){0.f, 0.f, 0.f, 0.f};                                 \
        aA = __builtin_amdgcn_mfma_f32_16x16x32_bf16(g0, cA0, aA, 0, 0, 0);     \
        aB = __builtin_amdgcn_mfma_f32_16x16x32_bf16(g0, cB0, aB, 0, 0, 0);     \
        aA = __builtin_amdgcn_mfma_f32_16x16x32_bf16(g1, cA1, aA, 0, 0, 0);     \
        aB = __builtin_amdgcn_mfma_f32_16x16x32_bf16(g1, cB1, aB, 0, 0, 0);     \
        aA = __builtin_amdgcn_mfma_f32_16x16x32_bf16(g2, cA2, aA, 0, 0, 0);     \
        aB = __builtin_amdgcn_mfma_f32_16x16x32_bf16(g2, cB2, aB, 0, 0, 0);     \
        aA = __builtin_amdgcn_mfma_f32_16x16x32_bf16(g3, cA3, aA, 0, 0, 0);     \
        aB = __builtin_amdgcn_mfma_f32_16x16x32_bf16(g3, cB3, aB, 0, 0, 0);     \
        const int _o = ((CT) & 1) * 4;                                          \
        esA += aA[0] * (float)XA[_o + 0] + aA[1] * (float)XA[_o + 1]            \
             + aA[2] * (float)XA[_o + 2] + aA[3] * (float)XA[_o + 3];           \
        esB += aB[0] * (float)XB[_o + 0] + aB[1] * (float)XB[_o + 1]            \
             + aB[2] * (float)XB[_o + 2] + aB[3] * (float)XB[_o + 3];           \
    }

// ---------------- main kernel: G in LDS, 32 atoms/wave-tile, 1-ahead prefetch ----------------

__global__ __launch_bounds__(BLOCK, 3) void k_main(
    const float* __restrict__ ps,
    const __bf16* __restrict__ gfrag,
    const int* __restrict__ species,
    const int* __restrict__ sids,
    float* __restrict__ out,
    int n)
{
    __shared__ __align__(16) __bf16 Glds[NSPEC * 128 * 128];   // 128 KB

    for (int f = threadIdx.x; f < 8192; f += BLOCK)
        ((int4*)Glds)[f] = ((const int4*)gfrag)[f];
    __syncthreads();

    const int lane = threadIdx.x & 63;
    const int r = lane & 15, g = lane >> 4;
    const int wid = blockIdx.x * (BLOCK / 64) + (threadIdx.x >> 6);
    const int gs = GRID * (BLOCK / 64);
    const int ntiles = (n + 31) / 32;

    int t = wid;
    if (t >= ntiles) return;

    const float4 z4 = make_float4(0.f, 0.f, 0.f, 0.f);

    int spcA, sidA, spcB, sidB;
    bool vA, vB;
    float nnA, nnB;
    float4 qa0, qa1, qa2, qa3, qa4, qa5, qa6, qa7;
    float4 qb0, qb1, qb2, qb3, qb4, qb5, qb6, qb7;
    bf16x8 cA0, cA1, cA2, cA3, cB0, cB1, cB2, cB3;

    // ---- prologue ----
    PREF_SET(t * 32, 0,  spcA, sidA, vA, qa0, qa1, qa2, qa3, qa4, qa5, qa6, qa7)
    PREF_SET(t * 32, 16, spcB, sidB, vB, qb0, qb1, qb2, qb3, qb4, qb5, qb6, qb7)
    CONSUME_SET(nnA, cA0, cA1, cA2, cA3, qa0, qa1, qa2, qa3, qa4, qa5, qa6, qa7)
    CONSUME_SET(nnB, cB0, cB1, cB2, cB3, qb0, qb1, qb2, qb3, qb4, qb5, qb6, qb7)

    for (; t < ntiles; t += gs) {
        const int spcAc = spcA, sidAc = sidA, spcBc = spcB, sidBc = sidB;
        const bool vAc = vA, vBc = vB;
        const float nnAc = nnA, nnBc = nnB;

        // ---- issue next tile's raw loads (waitcnt lands at the tail consume) ----
        const int tn = t + gs;
        if (tn < ntiles) {
            PREF_SET(tn * 32, 0,  spcA, sidA, vA, qa0, qa1, qa2, qa3, qa4, qa5, qa6, qa7)
            PREF_SET(tn * 32, 16, spcB, sidB, vB, qb0, qb1, qb2, qb3, qb4, qb5, qb6, qb7)
        }

        // ---- compute: 4 species x 8 ct-steps, G reads shared by both sets ----
        float eA = 0.f, eB = 0.f;
        #pragma unroll 1
        for (int s = 0; s < NSPEC; ++s) {
            const __bf16* gp = Glds + s * 16384 + lane * 8;
            float esA = 0.f, esB = 0.f;
            GSTEP2(0, cA0, cB0)
            GSTEP2(1, cA0, cB0)
            __builtin_amdgcn_sched_barrier(0);
            GSTEP2(2, cA1, cB1)
            GSTEP2(3, cA1, cB1)
            __builtin_amdgcn_sched_barrier(0);
            GSTEP2(4, cA2, cB2)
            GSTEP2(5, cA2, cB2)
            __builtin_amdgcn_sched_barrier(0);
            GSTEP2(6, cA3, cB3)
            GSTEP2(7, cA3, cB3)
            eA += (spcAc == s) ? esA : 0.f;
            eB += (spcBc == s) ? esB : 0.f;
        }

        float uA = (nnAc > 0.f) ? eA / nnAc : 0.f;
        float uB = (nnBc > 0.f) ? eB / nnBc : 0.f;

        // ---- emit ----
        const int s0 = __shfl(sidAc, 0);
        const bool uni = __all(sidAc == s0) && __all(sidBc == s0);
        if (uni) {
            float tot = uA + uB;
            tot += __shfl_xor(tot, 1);  tot += __shfl_xor(tot, 2);
            tot += __shfl_xor(tot, 4);  tot += __shfl_xor(tot, 8);
            tot += __shfl_xor(tot, 16); tot += __shfl_xor(tot, 32);
            if (lane == 0 && tot != 0.f) atomicAdd(&out[s0], tot);
        } else {
            uA += __shfl_xor(uA, 16); uA += __shfl_xor(uA, 32);
            uB += __shfl_xor(uB, 16); uB += __shfl_xor(uB, 32);
            if (g == 0) {
                if (vAc) atomicAdd(&out[sidAc], uA);
                if (vBc) atomicAdd(&out[sidBc], uB);
            }
        }

        // ---- consume prefetch for next iteration ----
        if (tn < ntiles) {
            CONSUME_SET(nnA, cA0, cA1, cA2, cA3, qa0, qa1, qa2, qa3, qa4, qa5, qa6, qa7)
            CONSUME_SET(nnB, cB0, cB1, cB2, cB3, qb0, qb1, qb2, qb3, qb4, qb5, qb6, qb7)
        }
    }
}

// ---------------- slow-but-correct fallback (ws too small) ----------------

__global__ void k_fallback(const float* __restrict__ ps, const float* __restrict__ support,
                           const float* __restrict__ weights, const int* __restrict__ species,
                           const int* __restrict__ struct_ids, float* __restrict__ out, int n)
{
    int gw = (blockIdx.x * blockDim.x + threadIdx.x) >> 6;
    int lane = threadIdx.x & 63;
    int nw = (gridDim.x * blockDim.x) >> 6;
    for (int atom = gw; atom < n; atom += nw) {
        const float* row = ps + (size_t)atom * KF;
        float x0 = row[lane], x1 = row[lane + 64];
        float nsum = x0 * x0 + x1 * x1;
        for (int o = 32; o; o >>= 1) nsum += __shfl_xor(nsum, o);
        float iv2 = 1.0f / nsum;
        int s = species[atom];
        const float* sup = support + (size_t)s * NSUP * KF;
        const float* w = weights + (size_t)s * NSUP;
        float e = 0.f;
        for (int mm = 0; mm < 4; ++mm) {
            int m = lane + mm * 64;
            const float* srow = sup + (size_t)m * KF;
            float d = 0.f;
            for (int k = 0; k < KF; ++k) d += row[k] * srow[k];
            e += d * d * w[m];
        }
        for (int o = 32; o; o >>= 1) e += __shfl_xor(e, o);
        if (lane == 0) atomicAdd(&out[struct_ids[atom]], e * iv2);
    }
}

// ---------------- launch ----------------

extern "C" void kernel_launch(void* const* d_in, const int* in_sizes, int n_in,
                              void* d_out, int out_size, void* d_ws, size_t ws_size,
                              hipStream_t stream)
{
    const float* ps       = (const float*)d_in[0];
    const float* support  = (const float*)d_in[1];
    const float* weights  = (const float*)d_in[2];
    const int*   species  = (const int*)d_in[3];
    const int*   sids     = (const int*)d_in[4];
    float* out = (float*)d_out;
    const int n = in_sizes[0] / KF;

    hipMemsetAsync(d_out, 0, (size_t)out_size * sizeof(float), stream);

    const size_t gbytes = (size_t)NSPEC * 8 * 4 * 64 * 8 * sizeof(__bf16);   // 128 KB
    if (ws_size < gbytes) {
        k_fallback<<<2048, 256, 0, stream>>>(ps, support, weights, species, sids, out, n);
        return;
    }

    __bf16* gfrag = (__bf16*)d_ws;
    k_buildG<<<(NSPEC * 8 * 4 * 64 + 255) / 256, 256, 0, stream>>>(support, weights, gfrag);
    k_main<<<GRID, BLOCK, 0, stream>>>(ps, gfrag, species, sids, out, n);
}

// Round 14
// 305.074 us; speedup vs baseline: 1.0977x; 1.0977x over previous
//
#include <hip/hip_runtime.h>

#define KF 128
#define NSUP 256
#define NSPEC 4
#define GRID 256      // 1 block per CU (LDS-capped)
#define BLOCK 1024    // 16 waves -> 4 waves/SIMD

typedef __bf16 bf16x8 __attribute__((ext_vector_type(8)));
typedef float  f32x4  __attribute__((ext_vector_type(4)));

// ---------------- build per-species Gram matrix, sigma-permuted fragment-major ----------------
// G[s][c][k] = sum_m w[s][m]*sup[s][m][c]*sup[s][m][k]  (fp32 accum -> bf16)
// t = ((s*8+ct)*4+kk)*64+lane holds G[s][sigma(ct,lane&15)][kk*32+(lane>>4)*8+u], u=0..7
// sigma(ct,i) = (ct>>1)*32 + (i>>2)*8 + (ct&1)*4 + (i&3): MFMA D-layout lands z[c] on
// the lane that already holds x[c] -> pairing needs no cross-lane moves.

__global__ void k_buildG(const float* __restrict__ sup, const float* __restrict__ w,
                         __bf16* __restrict__ gfrag) {
    const int t = blockIdx.x * blockDim.x + threadIdx.x;   // 8192 total
    if (t >= NSPEC * 8 * 4 * 64) return;
    const int lane = t & 63;
    const int kk   = (t >> 6) & 3;
    const int ct   = (t >> 8) & 7;
    const int s    = t >> 11;
    const int i    = lane & 15;
    const int c    = (ct >> 1) * 32 + (i >> 2) * 8 + (ct & 1) * 4 + (i & 3);
    const int k0   = kk * 32 + (lane >> 4) * 8;
    const float* S = sup + (size_t)s * NSUP * KF;
    const float* W = w + s * NSUP;
    float a0 = 0.f, a1 = 0.f, a2 = 0.f, a3 = 0.f, a4 = 0.f, a5 = 0.f, a6 = 0.f, a7 = 0.f;
    for (int m = 0; m < NSUP; ++m) {
        const float wc = W[m] * S[m * KF + c];
        const float4 ka = *(const float4*)(S + m * KF + k0);
        const float4 kb = *(const float4*)(S + m * KF + k0 + 4);
        a0 += wc * ka.x; a1 += wc * ka.y; a2 += wc * ka.z; a3 += wc * ka.w;
        a4 += wc * kb.x; a5 += wc * kb.y; a6 += wc * kb.z; a7 += wc * kb.w;
    }
    bf16x8 o;
    o[0] = (__bf16)a0; o[1] = (__bf16)a1; o[2] = (__bf16)a2; o[3] = (__bf16)a3;
    o[4] = (__bf16)a4; o[5] = (__bf16)a5; o[6] = (__bf16)a6; o[7] = (__bf16)a7;
    *(bf16x8*)(gfrag + (size_t)t * 8) = o;
}

// ---------------- helpers ----------------

__device__ __forceinline__ bf16x8 pack8(float4 a, float4 b) {
    bf16x8 o;
    o[0] = (__bf16)a.x; o[1] = (__bf16)a.y; o[2] = (__bf16)a.z; o[3] = (__bf16)a.w;
    o[4] = (__bf16)b.x; o[5] = (__bf16)b.y; o[6] = (__bf16)b.z; o[7] = (__bf16)b.w;
    return o;
}

__device__ __forceinline__ float sq4(float4 a) {
    return a.x * a.x + a.y * a.y + a.z * a.z + a.w * a.w;
}

// Load one 16-atom set: meta + 4 bf16x8 fragments + fp32 norm. Loads are consumed
// pairwise (norm+pack) so the float4 temporaries stay short-lived.
#define LOAD_SET(BASE, OFF, SPC, SID, V, NN, X0, X1, X2, X3)              \
    {                                                                     \
        int _a = (BASE) + (OFF) + r;                                      \
        V = _a < n;                                                       \
        int _ra = V ? _a : 0;                                             \
        SPC = V ? species[_ra] : -1;                                      \
        SID = V ? sids[_ra] : 0;                                          \
        const float* _p = ps + (size_t)_ra * KF + g * 8;                  \
        float4 _q0 = V ? *(const float4*)(_p +   0) : z4;                 \
        float4 _q1 = V ? *(const float4*)(_p +   4) : z4;                 \
        float4 _q2 = V ? *(const float4*)(_p +  32) : z4;                 \
        float4 _q3 = V ? *(const float4*)(_p +  36) : z4;                 \
        float4 _q4 = V ? *(const float4*)(_p +  64) : z4;                 \
        float4 _q5 = V ? *(const float4*)(_p +  68) : z4;                 \
        float4 _q6 = V ? *(const float4*)(_p +  96) : z4;                 \
        float4 _q7 = V ? *(const float4*)(_p + 100) : z4;                 \
        NN = sq4(_q0) + sq4(_q1) + sq4(_q2) + sq4(_q3)                    \
           + sq4(_q4) + sq4(_q5) + sq4(_q6) + sq4(_q7);                   \
        NN += __shfl_xor(NN, 16);                                         \
        NN += __shfl_xor(NN, 32);                                         \
        X0 = pack8(_q0, _q1); X1 = pack8(_q2, _q3);                       \
        X2 = pack8(_q4, _q5); X3 = pack8(_q6, _q7);                       \
    }

// One ct-step for BOTH atom-sets: 4 G-fragment LDS reads feed 8 MFMA.
// Pairing scalars come from fragment XA/XB elements (CT&1)*4 .. +3.
#define GSTEP2(CT, XA, XB)                                                      \
    {                                                                           \
        const __bf16* gq = gp + (CT) * 2048;                                    \
        const bf16x8 g0 = *(const bf16x8*)(gq);                                 \
        const bf16x8 g1 = *(const bf16x8*)(gq + 512);                           \
        const bf16x8 g2 = *(const bf16x8*)(gq + 1024);                          \
        const bf16x8 g3 = *(const bf16x8*)(gq + 1536);                          \
        f32x4 aA = (f32x4){0.f, 0.f, 0.f, 0.f};                                 \
        f32x4 aB = (f32x4){0.f, 0.f, 0.f, 0.f};                                 \
        aA = __builtin_amdgcn_mfma_f32_16x16x32_bf16(g0, cA0, aA, 0, 0, 0);     \
        aB = __builtin_amdgcn_mfma_f32_16x16x32_bf16(g0, cB0, aB, 0, 0, 0);     \
        aA = __builtin_amdgcn_mfma_f32_16x16x32_bf16(g1, cA1, aA, 0, 0, 0);     \
        aB = __builtin_amdgcn_mfma_f32_16x16x32_bf16(g1, cB1, aB, 0, 0, 0);     \
        aA = __builtin_amdgcn_mfma_f32_16x16x32_bf16(g2, cA2, aA, 0, 0, 0);     \
        aB = __builtin_amdgcn_mfma_f32_16x16x32_bf16(g2, cB2, aB, 0, 0, 0);     \
        aA = __builtin_amdgcn_mfma_f32_16x16x32_bf16(g3, cA3, aA, 0, 0, 0);     \
        aB = __builtin_amdgcn_mfma_f32_16x16x32_bf16(g3, cB3, aB, 0, 0, 0);     \
        const int _o = ((CT) & 1) * 4;                                          \
        esA += aA[0] * (float)XA[_o + 0] + aA[1] * (float)XA[_o + 1]            \
             + aA[2] * (float)XA[_o + 2] + aA[3] * (float)XA[_o + 3];           \
        esB += aB[0] * (float)XB[_o + 0] + aB[1] * (float)XB[_o + 1]            \
             + aB[2] * (float)XB[_o + 2] + aB[3] * (float)XB[_o + 3];           \
    }

// ---------------- main kernel: G in LDS, 32 atoms/wave-tile, TLP-covered loads ----------------

__global__ __launch_bounds__(BLOCK, 4) void k_main(
    const float* __restrict__ ps,
    const __bf16* __restrict__ gfrag,
    const int* __restrict__ species,
    const int* __restrict__ sids,
    float* __restrict__ out,
    int n)
{
    __shared__ __align__(16) __bf16 Glds[NSPEC * 128 * 128];   // 128 KB

    for (int f = threadIdx.x; f < 8192; f += BLOCK)
        ((int4*)Glds)[f] = ((const int4*)gfrag)[f];
    __syncthreads();

    const int lane = threadIdx.x & 63;
    const int r = lane & 15, g = lane >> 4;
    const int wid = blockIdx.x * (BLOCK / 64) + (threadIdx.x >> 6);
    const int gs = GRID * (BLOCK / 64);
    const int ntiles = (n + 31) / 32;

    const float4 z4 = make_float4(0.f, 0.f, 0.f, 0.f);

    for (int t = wid; t < ntiles; t += gs) {
        int spcA, sidA, spcB, sidB;
        bool vA, vB;
        float nnA, nnB;
        bf16x8 cA0, cA1, cA2, cA3, cB0, cB1, cB2, cB3;

        LOAD_SET(t * 32, 0,  spcA, sidA, vA, nnA, cA0, cA1, cA2, cA3)
        LOAD_SET(t * 32, 16, spcB, sidB, vB, nnB, cB0, cB1, cB2, cB3)

        // ---- compute: 4 species x 8 ct-steps, G reads shared by both sets ----
        float eA = 0.f, eB = 0.f;
        #pragma unroll 1
        for (int s = 0; s < NSPEC; ++s) {
            const __bf16* gp = Glds + s * 16384 + lane * 8;
            float esA = 0.f, esB = 0.f;
            GSTEP2(0, cA0, cB0)
            GSTEP2(1, cA0, cB0)
            __builtin_amdgcn_sched_barrier(0);
            GSTEP2(2, cA1, cB1)
            GSTEP2(3, cA1, cB1)
            __builtin_amdgcn_sched_barrier(0);
            GSTEP2(4, cA2, cB2)
            GSTEP2(5, cA2, cB2)
            __builtin_amdgcn_sched_barrier(0);
            GSTEP2(6, cA3, cB3)
            GSTEP2(7, cA3, cB3)
            eA += (spcA == s) ? esA : 0.f;
            eB += (spcB == s) ? esB : 0.f;
        }

        float uA = (nnA > 0.f) ? eA / nnA : 0.f;
        float uB = (nnB > 0.f) ? eB / nnB : 0.f;

        // ---- emit ----
        const int s0 = __shfl(sidA, 0);
        const bool uni = __all(sidA == s0) && __all(sidB == s0);
        if (uni) {
            float tot = uA + uB;
            tot += __shfl_xor(tot, 1);  tot += __shfl_xor(tot, 2);
            tot += __shfl_xor(tot, 4);  tot += __shfl_xor(tot, 8);
            tot += __shfl_xor(tot, 16); tot += __shfl_xor(tot, 32);
            if (lane == 0 && tot != 0.f) atomicAdd(&out[s0], tot);
        } else {
            uA += __shfl_xor(uA, 16); uA += __shfl_xor(uA, 32);
            uB += __shfl_xor(uB, 16); uB += __shfl_xor(uB, 32);
            if (g == 0) {
                if (vA) atomicAdd(&out[sidA], uA);
                if (vB) atomicAdd(&out[sidB], uB);
            }
        }
    }
}

// ---------------- slow-but-correct fallback (ws too small) ----------------

__global__ void k_fallback(const float* __restrict__ ps, const float* __restrict__ support,
                           const float* __restrict__ weights, const int* __restrict__ species,
                           const int* __restrict__ struct_ids, float* __restrict__ out, int n)
{
    int gw = (blockIdx.x * blockDim.x + threadIdx.x) >> 6;
    int lane = threadIdx.x & 63;
    int nw = (gridDim.x * blockDim.x) >> 6;
    for (int atom = gw; atom < n; atom += nw) {
        const float* row = ps + (size_t)atom * KF;
        float x0 = row[lane], x1 = row[lane + 64];
        float nsum = x0 * x0 + x1 * x1;
        for (int o = 32; o; o >>= 1) nsum += __shfl_xor(nsum, o);
        float iv2 = 1.0f / nsum;
        int s = species[atom];
        const float* sup = support + (size_t)s * NSUP * KF;
        const float* w = weights + (size_t)s * NSUP;
        float e = 0.f;
        for (int mm = 0; mm < 4; ++mm) {
            int m = lane + mm * 64;
            const float* srow = sup + (size_t)m * KF;
            float d = 0.f;
            for (int k = 0; k < KF; ++k) d += row[k] * srow[k];
            e += d * d * w[m];
        }
        for (int o = 32; o; o >>= 1) e += __shfl_xor(e, o);
        if (lane == 0) atomicAdd(&out[struct_ids[atom]], e * iv2);
    }
}

// ---------------- launch ----------------

extern "C" void kernel_launch(void* const* d_in, const int* in_sizes, int n_in,
                              void* d_out, int out_size, void* d_ws, size_t ws_size,
                              hipStream_t stream)
{
    const float* ps       = (const float*)d_in[0];
    const float* support  = (const float*)d_in[1];
    const float* weights  = (const float*)d_in[2];
    const int*   species  = (const int*)d_in[3];
    const int*   sids     = (const int*)d_in[4];
    float* out = (float*)d_out;
    const int n = in_sizes[0] / KF;

    hipMemsetAsync(d_out, 0, (size_t)out_size * sizeof(float), stream);

    const size_t gbytes = (size_t)NSPEC * 8 * 4 * 64 * 8 * sizeof(__bf16);   // 128 KB
    if (ws_size < gbytes) {
        k_fallback<<<2048, 256, 0, stream>>>(ps, support, weights, species, sids, out, n);
        return;
    }

    __bf16* gfrag = (__bf16*)d_ws;
    k_buildG<<<(NSPEC * 8 * 4 * 64 + 255) / 256, 256, 0, stream>>>(support, weights, gfrag);
    k_main<<<GRID, BLOCK, 0, stream>>>(ps, gfrag, species, sids, out, n);
}

// Round 15
// 194.907 us; speedup vs baseline: 1.7182x; 1.5652x over previous
//
#include <hip/hip_runtime.h>

#define KF 128
#define NSUP 256
#define NSPEC 4
#define GRID 256      // 1 block per CU (LDS-capped)
#define BLOCK 512     // 8 waves -> 2 waves/SIMD; <=512 threads keeps hipcc's
                      // register heuristic sane (r11: VGPR 88, zero spill;
                      // >=768-thread blocks clamp to 64-84 VGPR and spill GBs)

typedef __bf16 bf16x8 __attribute__((ext_vector_type(8)));
typedef float  f32x4  __attribute__((ext_vector_type(4)));

// ---------------- build per-species Gram matrix, sigma-permuted fragment-major ----------------
// G[s][c][k] = sum_m w[s][m]*sup[s][m][c]*sup[s][m][k]  (fp32 accum -> bf16)
// t = ((s*8+ct)*4+kk)*64+lane holds G[s][sigma(ct,lane&15)][kk*32+(lane>>4)*8+u], u=0..7
// sigma(ct,i) = (ct>>1)*32 + (i>>2)*8 + (ct&1)*4 + (i&3): MFMA D-layout lands z[c] on
// the lane that already holds x[c] -> pairing needs no cross-lane moves.

__global__ void k_buildG(const float* __restrict__ sup, const float* __restrict__ w,
                         __bf16* __restrict__ gfrag) {
    const int t = blockIdx.x * blockDim.x + threadIdx.x;   // 8192 total
    if (t >= NSPEC * 8 * 4 * 64) return;
    const int lane = t & 63;
    const int kk   = (t >> 6) & 3;
    const int ct   = (t >> 8) & 7;
    const int s    = t >> 11;
    const int i    = lane & 15;
    const int c    = (ct >> 1) * 32 + (i >> 2) * 8 + (ct & 1) * 4 + (i & 3);
    const int k0   = kk * 32 + (lane >> 4) * 8;
    const float* S = sup + (size_t)s * NSUP * KF;
    const float* W = w + s * NSUP;
    float a0 = 0.f, a1 = 0.f, a2 = 0.f, a3 = 0.f, a4 = 0.f, a5 = 0.f, a6 = 0.f, a7 = 0.f;
    for (int m = 0; m < NSUP; ++m) {
        const float wc = W[m] * S[m * KF + c];
        const float4 ka = *(const float4*)(S + m * KF + k0);
        const float4 kb = *(const float4*)(S + m * KF + k0 + 4);
        a0 += wc * ka.x; a1 += wc * ka.y; a2 += wc * ka.z; a3 += wc * ka.w;
        a4 += wc * kb.x; a5 += wc * kb.y; a6 += wc * kb.z; a7 += wc * kb.w;
    }
    bf16x8 o;
    o[0] = (__bf16)a0; o[1] = (__bf16)a1; o[2] = (__bf16)a2; o[3] = (__bf16)a3;
    o[4] = (__bf16)a4; o[5] = (__bf16)a5; o[6] = (__bf16)a6; o[7] = (__bf16)a7;
    *(bf16x8*)(gfrag + (size_t)t * 8) = o;
}

// ---------------- helpers ----------------

__device__ __forceinline__ bf16x8 pack8(float4 a, float4 b) {
    bf16x8 o;
    o[0] = (__bf16)a.x; o[1] = (__bf16)a.y; o[2] = (__bf16)a.z; o[3] = (__bf16)a.w;
    o[4] = (__bf16)b.x; o[5] = (__bf16)b.y; o[6] = (__bf16)b.z; o[7] = (__bf16)b.w;
    return o;
}

__device__ __forceinline__ float sq4(float4 a) {
    return a.x * a.x + a.y * a.y + a.z * a.z + a.w * a.w;
}

// Load one 16-atom set: meta + 4 bf16x8 fragments + fp32 norm. Loads are consumed
// pairwise (norm+pack) so the float4 temporaries stay short-lived.
#define LOAD_SET(BASE, OFF, SPC, SID, V, NN, X0, X1, X2, X3)              \
    {                                                                     \
        int _a = (BASE) + (OFF) + r;                                      \
        V = _a < n;                                                       \
        int _ra = V ? _a : 0;                                             \
        SPC = V ? species[_ra] : -1;                                      \
        SID = V ? sids[_ra] : 0;                                          \
        const float* _p = ps + (size_t)_ra * KF + g * 8;                  \
        float4 _q0 = V ? *(const float4*)(_p +   0) : z4;                 \
        float4 _q1 = V ? *(const float4*)(_p +   4) : z4;                 \
        float4 _q2 = V ? *(const float4*)(_p +  32) : z4;                 \
        float4 _q3 = V ? *(const float4*)(_p +  36) : z4;                 \
        float4 _q4 = V ? *(const float4*)(_p +  64) : z4;                 \
        float4 _q5 = V ? *(const float4*)(_p +  68) : z4;                 \
        float4 _q6 = V ? *(const float4*)(_p +  96) : z4;                 \
        float4 _q7 = V ? *(const float4*)(_p + 100) : z4;                 \
        NN = sq4(_q0) + sq4(_q1) + sq4(_q2) + sq4(_q3)                    \
           + sq4(_q4) + sq4(_q5) + sq4(_q6) + sq4(_q7);                   \
        NN += __shfl_xor(NN, 16);                                         \
        NN += __shfl_xor(NN, 32);                                         \
        X0 = pack8(_q0, _q1); X1 = pack8(_q2, _q3);                       \
        X2 = pack8(_q4, _q5); X3 = pack8(_q6, _q7);                       \
    }

// One ct-step for BOTH atom-sets: 4 G-fragment LDS reads feed 8 MFMA.
// Pairing scalars come from fragment XA/XB elements (CT&1)*4 .. +3.
#define GSTEP2(CT, XA, XB)                                                      \
    {                                                                           \
        const __bf16* gq = gp + (CT) * 2048;                                    \
        const bf16x8 g0 = *(const bf16x8*)(gq);                                 \
        const bf16x8 g1 = *(const bf16x8*)(gq + 512);                           \
        const bf16x8 g2 = *(const bf16x8*)(gq + 1024);                          \
        const bf16x8 g3 = *(const bf16x8*)(gq + 1536);                          \
        f32x4 aA = (f32x4){0.f, 0.f, 0.f, 0.f};                                 \
        f32x4 aB = (f32x4){0.f, 0.f, 0.f, 0.f};                                 \
        aA = __builtin_amdgcn_mfma_f32_16x16x32_bf16(g0, cA0, aA, 0, 0, 0);     \
        aB = __builtin_amdgcn_mfma_f32_16x16x32_bf16(g0, cB0, aB, 0, 0, 0);     \
        aA = __builtin_amdgcn_mfma_f32_16x16x32_bf16(g1, cA1, aA, 0, 0, 0);     \
        aB = __builtin_amdgcn_mfma_f32_16x16x32_bf16(g1, cB1, aB, 0, 0, 0);     \
        aA = __builtin_amdgcn_mfma_f32_16x16x32_bf16(g2, cA2, aA, 0, 0, 0);     \
        aB = __builtin_amdgcn_mfma_f32_16x16x32_bf16(g2, cB2, aB, 0, 0, 0);     \
        aA = __builtin_amdgcn_mfma_f32_16x16x32_bf16(g3, cA3, aA, 0, 0, 0);     \
        aB = __builtin_amdgcn_mfma_f32_16x16x32_bf16(g3, cB3, aB, 0, 0, 0);     \
        const int _o = ((CT) & 1) * 4;                                          \
        esA += aA[0] * (float)XA[_o + 0] + aA[1] * (float)XA[_o + 1]            \
             + aA[2] * (float)XA[_o + 2] + aA[3] * (float)XA[_o + 3];           \
        esB += aB[0] * (float)XB[_o + 0] + aB[1] * (float)XB[_o + 1]            \
             + aB[2] * (float)XB[_o + 2] + aB[3] * (float)XB[_o + 3];           \
    }

// ---------------- main kernel: G in LDS, 32 atoms/wave-tile, TLP-covered loads ----------------

__global__ __launch_bounds__(BLOCK, 1) void k_main(
    const float* __restrict__ ps,
    const __bf16* __restrict__ gfrag,
    const int* __restrict__ species,
    const int* __restrict__ sids,
    float* __restrict__ out,
    int n)
{
    __shared__ __align__(16) __bf16 Glds[NSPEC * 128 * 128];   // 128 KB

    for (int f = threadIdx.x; f < 8192; f += BLOCK)
        ((int4*)Glds)[f] = ((const int4*)gfrag)[f];
    __syncthreads();

    const int lane = threadIdx.x & 63;
    const int r = lane & 15, g = lane >> 4;
    const int wid = blockIdx.x * (BLOCK / 64) + (threadIdx.x >> 6);
    const int gs = GRID * (BLOCK / 64);
    const int ntiles = (n + 31) / 32;

    const float4 z4 = make_float4(0.f, 0.f, 0.f, 0.f);

    for (int t = wid; t < ntiles; t += gs) {
        int spcA, sidA, spcB, sidB;
        bool vA, vB;
        float nnA, nnB;
        bf16x8 cA0, cA1, cA2, cA3, cB0, cB1, cB2, cB3;

        LOAD_SET(t * 32, 0,  spcA, sidA, vA, nnA, cA0, cA1, cA2, cA3)
        LOAD_SET(t * 32, 16, spcB, sidB, vB, nnB, cB0, cB1, cB2, cB3)

        // ---- compute: 4 species x 8 ct-steps, G reads shared by both sets ----
        float eA = 0.f, eB = 0.f;
        #pragma unroll 1
        for (int s = 0; s < NSPEC; ++s) {
            const __bf16* gp = Glds + s * 16384 + lane * 8;
            float esA = 0.f, esB = 0.f;
            GSTEP2(0, cA0, cB0)
            GSTEP2(1, cA0, cB0)
            __builtin_amdgcn_sched_barrier(0);
            GSTEP2(2, cA1, cB1)
            GSTEP2(3, cA1, cB1)
            __builtin_amdgcn_sched_barrier(0);
            GSTEP2(4, cA2, cB2)
            GSTEP2(5, cA2, cB2)
            __builtin_amdgcn_sched_barrier(0);
            GSTEP2(6, cA3, cB3)
            GSTEP2(7, cA3, cB3)
            eA += (spcA == s) ? esA : 0.f;
            eB += (spcB == s) ? esB : 0.f;
        }

        float uA = (nnA > 0.f) ? eA / nnA : 0.f;
        float uB = (nnB > 0.f) ? eB / nnB : 0.f;

        // ---- emit ----
        const int s0 = __shfl(sidA, 0);
        const bool uni = __all(sidA == s0) && __all(sidB == s0);
        if (uni) {
            float tot = uA + uB;
            tot += __shfl_xor(tot, 1);  tot += __shfl_xor(tot, 2);
            tot += __shfl_xor(tot, 4);  tot += __shfl_xor(tot, 8);
            tot += __shfl_xor(tot, 16); tot += __shfl_xor(tot, 32);
            if (lane == 0 && tot != 0.f) atomicAdd(&out[s0], tot);
        } else {
            uA += __shfl_xor(uA, 16); uA += __shfl_xor(uA, 32);
            uB += __shfl_xor(uB, 16); uB += __shfl_xor(uB, 32);
            if (g == 0) {
                if (vA) atomicAdd(&out[sidA], uA);
                if (vB) atomicAdd(&out[sidB], uB);
            }
        }
    }
}

// ---------------- slow-but-correct fallback (ws too small) ----------------

__global__ void k_fallback(const float* __restrict__ ps, const float* __restrict__ support,
                           const float* __restrict__ weights, const int* __restrict__ species,
                           const int* __restrict__ struct_ids, float* __restrict__ out, int n)
{
    int gw = (blockIdx.x * blockDim.x + threadIdx.x) >> 6;
    int lane = threadIdx.x & 63;
    int nw = (gridDim.x * blockDim.x) >> 6;
    for (int atom = gw; atom < n; atom += nw) {
        const float* row = ps + (size_t)atom * KF;
        float x0 = row[lane], x1 = row[lane + 64];
        float nsum = x0 * x0 + x1 * x1;
        for (int o = 32; o; o >>= 1) nsum += __shfl_xor(nsum, o);
        float iv2 = 1.0f / nsum;
        int s = species[atom];
        const float* sup = support + (size_t)s * NSUP * KF;
        const float* w = weights + (size_t)s * NSUP;
        float e = 0.f;
        for (int mm = 0; mm < 4; ++mm) {
            int m = lane + mm * 64;
            const float* srow = sup + (size_t)m * KF;
            float d = 0.f;
            for (int k = 0; k < KF; ++k) d += row[k] * srow[k];
            e += d * d * w[m];
        }
        for (int o = 32; o; o >>= 1) e += __shfl_xor(e, o);
        if (lane == 0) atomicAdd(&out[struct_ids[atom]], e * iv2);
    }
}

// ---------------- launch ----------------

extern "C" void kernel_launch(void* const* d_in, const int* in_sizes, int n_in,
                              void* d_out, int out_size, void* d_ws, size_t ws_size,
                              hipStream_t stream)
{
    const float* ps       = (const float*)d_in[0];
    const float* support  = (const float*)d_in[1];
    const float* weights  = (const float*)d_in[2];
    const int*   species  = (const int*)d_in[3];
    const int*   sids     = (const int*)d_in[4];
    float* out = (float*)d_out;
    const int n = in_sizes[0] / KF;

    hipMemsetAsync(d_out, 0, (size_t)out_size * sizeof(float), stream);

    const size_t gbytes = (size_t)NSPEC * 8 * 4 * 64 * 8 * sizeof(__bf16);   // 128 KB
    if (ws_size < gbytes) {
        k_fallback<<<2048, 256, 0, stream>>>(ps, support, weights, species, sids, out, n);
        return;
    }

    __bf16* gfrag = (__bf16*)d_ws;
    k_buildG<<<(NSPEC * 8 * 4 * 64 + 255) / 256, 256, 0, stream>>>(support, weights, gfrag);
    k_main<<<GRID, BLOCK, 0, stream>>>(ps, gfrag, species, sids, out, n);
}